// Round 15
// baseline (265.501 us; speedup 1.0000x reference)
//
#include <hip/hip_runtime.h>
#include <math.h>
#include <stdint.h>

#define B_ 16
#define D_ 1024
#define T_ 4096
#define CS_ 1024
#define CD_ 8

// ---------- numpy-mimicking fp32 helpers ----------
__device__ __forceinline__ float f_tree8(const float r[8]) {
  return __fadd_rn(
      __fadd_rn(__fadd_rn(r[0], r[1]), __fadd_rn(r[2], r[3])),
      __fadd_rn(__fadd_rn(r[4], r[5]), __fadd_rn(r[6], r[7])));
}
__device__ __forceinline__ float f_sumsq8(const float x[8]) {
  float s[8];
#pragma unroll
  for (int k = 0; k < 8; ++k) s[k] = __fmul_rn(x[k], x[k]);
  return f_tree8(s);
}

// ---------- setup (unchanged) ----------
__global__ __launch_bounds__(1024) void vq_setup(
    const float* __restrict__ cb, const float* __restrict__ g_in,
    const float* __restrict__ v_in, const float* __restrict__ g_out,
    const float* __restrict__ v_out, const float* __restrict__ b_out,
    double* __restrict__ WTd, float* __restrict__ cb16,
    float* __restrict__ wo16) {
  __shared__ float sv[8 * 1024];
  __shared__ float leafs[64];
  __shared__ float den[8];
  const int tid = threadIdx.x;

  for (int i = tid; i < 8 * 1024; i += 1024) sv[i] = v_in[i];
  __syncthreads();

  if (tid < 64) {
    const int c = tid >> 3, l = tid & 7;
    const float* a = sv + c * 1024 + l * 128;
    float r[8];
#pragma unroll
    for (int k = 0; k < 8; ++k) r[k] = __fmul_rn(a[k], a[k]);
    for (int i = 8; i < 128; i += 8) {
#pragma unroll
      for (int k = 0; k < 8; ++k)
        r[k] = __fadd_rn(r[k], __fmul_rn(a[i + k], a[i + k]));
    }
    leafs[c * 8 + l] = f_tree8(r);
  }
  __syncthreads();
  if (tid < 8) {
    const float* L = leafs + tid * 8;
    float lr[8];
#pragma unroll
    for (int k = 0; k < 8; ++k) lr[k] = L[k];
    const float s = f_tree8(lr);
    den[tid] = fmaxf(__fsqrt_rn(s), 1e-12f);
  }
  __syncthreads();

  if (tid < 1024) {
#pragma unroll
    for (int c = 0; c < 8; ++c) {
      const float w = __fdiv_rn(__fmul_rn(g_in[c], sv[c * 1024 + tid]), den[c]);
      WTd[tid * 8 + c] = (double)w;
    }
    {
      const float* cr = cb + tid * 8;
      float q[8];
#pragma unroll
      for (int c = 0; c < 8; ++c) q[c] = cr[c];
      const float nn = f_sumsq8(q);
      const float dd = fmaxf(__fsqrt_rn(nn), 1e-12f);
      float qn[8];
#pragma unroll
      for (int c = 0; c < 8; ++c) {
        qn[c] = __fdiv_rn(q[c], dd);
        cb16[tid * 16 + c] = qn[c];
      }
      cb16[tid * 16 + 8] = f_sumsq8(qn);
#pragma unroll
      for (int c = 9; c < 16; ++c) cb16[tid * 16 + c] = 0.f;
    }
    {
      const float* vr = v_out + tid * 8;
      float w[8];
#pragma unroll
      for (int c = 0; c < 8; ++c) w[c] = vr[c];
      const float n2 = f_sumsq8(w);
      const float d2 = fmaxf(__fsqrt_rn(n2), 1e-12f);
      const float go = g_out[tid];
#pragma unroll
      for (int c = 0; c < 8; ++c)
        wo16[tid * 16 + c] = __fdiv_rn(__fmul_rn(go, w[c]), d2);
      wo16[tid * 16 + 8] = b_out[tid];
#pragma unroll
      for (int c = 9; c < 16; ++c) wo16[tid * 16 + c] = 0.f;
    }
  }
}

// ================= 3-kernel row-contiguous pipeline =================

// K1: partial z_e. Block = (b, slice s of 64 d, half h of 2048 t).
// 1024 thr x 2 t (float2). Block's z stream = 64 rows x 8 KB CONTIGUOUS
// chunks (waves cover adjacent 512-B windows) -> HBM channels spread,
// unlike the fused tiling where a block's whole stream sat in one fixed
// 512-B window (constant mod every pow2 >= 512 -> channel-serialized,
// the invariant 2.66 TB/s of R7-R14). No LDS, no barriers.
__global__ __launch_bounds__(1024, 8) void vq_part(
    const float* __restrict__ z, const double* __restrict__ WTd,
    double* __restrict__ pb) {
  const int tid = threadIdx.x;
  const int blk = blockIdx.x;  // b*32 + s*2 + h
  const int b = blk >> 5;
  const int s = (blk >> 1) & 15;
  const int h = blk & 1;
  const int t = h * 2048 + tid * 2;

  const float2* zp2 =
      (const float2*)(z + ((size_t)b * D_ + (size_t)s * 64) * T_ + t);
  const double* wd = WTd + (size_t)s * 512;  // uniform -> s_load

  double acc0[8], acc1[8];
#pragma unroll
  for (int c = 0; c < 8; ++c) { acc0[c] = 0.0; acc1[c] = 0.0; }

  float2 zA[8], zB[8];
#pragma unroll
  for (int u = 0; u < 8; ++u) zA[u] = zp2[(size_t)u * (T_ / 2)];

#pragma unroll
  for (int dc = 0; dc < 64; dc += 16) {
#pragma unroll
    for (int u = 0; u < 8; ++u)
      zB[u] = zp2[(size_t)(dc + 8 + u) * (T_ / 2)];
#pragma unroll
    for (int u = 0; u < 8; ++u) {
      const double* w = wd + (size_t)(dc + u) * 8;
      const double zx = (double)zA[u].x, zy = (double)zA[u].y;
#pragma unroll
      for (int c = 0; c < 8; ++c) {
        acc0[c] = fma(zx, w[c], acc0[c]);
        acc1[c] = fma(zy, w[c], acc1[c]);
      }
    }
    if (dc + 16 < 64) {
#pragma unroll
      for (int u = 0; u < 8; ++u)
        zA[u] = zp2[(size_t)(dc + 16 + u) * (T_ / 2)];
    }
#pragma unroll
    for (int u = 0; u < 8; ++u) {
      const double* w = wd + (size_t)(dc + 8 + u) * 8;
      const double zx = (double)zB[u].x, zy = (double)zB[u].y;
#pragma unroll
      for (int c = 0; c < 8; ++c) {
        acc0[c] = fma(zx, w[c], acc0[c]);
        acc1[c] = fma(zy, w[c], acc1[c]);
      }
    }
  }

  // partials: pb[(b*16+s)*8 + ch][t], coalesced double2 stores
  double* pbase = pb + ((size_t)(b * 16 + s) * 8) * T_ + t;
#pragma unroll
  for (int c = 0; c < 8; ++c) {
    double2 v; v.x = acc0[c]; v.y = acc1[c];
    *(double2*)(pbase + (size_t)c * T_) = v;
  }
}

// K2: reduce 16 slices (ascending, R10's chain regrouped by quarters --
// ~1e-16 perturbation vs the 1e-4 numpy-accumulation slack already
// tolerated), normalize, 1024-code first-min scan (quarter-split,
// ascending strict-<), idx + loss. Block = (b, 256-t chunk), 1024 thr =
// 4 code/slice-quarters x 256 t-lanes.
__global__ __launch_bounds__(1024, 4) void vq_red(
    const double* __restrict__ pb, const float* __restrict__ cbraw,
    const float* __restrict__ b_in, const float* __restrict__ cb16,
    float* __restrict__ oidx, float* __restrict__ lossp) {
  __shared__ double qpart[4][8][256];  // 64 KB
  __shared__ float enb[8][256];
  __shared__ float seb[256];
  __shared__ float cdist[4][256];
  __shared__ int cidx[4][256];
  __shared__ float lred[4];
  const int tid = threadIdx.x;
  const int qp = tid >> 8;      // quarter 0..3 (wave-uniform)
  const int tl = tid & 255;
  const int blk = blockIdx.x;   // b*16 + tc
  const int b = blk >> 4;
  const int tc = blk & 15;
  const int t = tc * 256 + tl;

  // phase A: quarter qp sums slices 4qp..4qp+3 (ascending)
  {
    double qs[8];
#pragma unroll
    for (int c = 0; c < 8; ++c) qs[c] = 0.0;
#pragma unroll
    for (int sl = 0; sl < 4; ++sl) {
      const int s = qp * 4 + sl;
      const double* p = pb + ((size_t)(b * 16 + s) * 8) * T_ + t;
#pragma unroll
      for (int c = 0; c < 8; ++c) qs[c] = qs[c] + p[(size_t)c * T_];
    }
#pragma unroll
    for (int c = 0; c < 8; ++c) qpart[qp][c][tl] = qs[c];
  }
  __syncthreads();

  // phase B (tid<256): combine quarters ascending, materialize z_e
  float e[8];
  if (tid < 256) {
    float en[8];
#pragma unroll
    for (int c = 0; c < 8; ++c) {
      double tot = qpart[0][c][tl];
#pragma unroll
      for (int q = 1; q < 4; ++q) tot = tot + qpart[q][c][tl];
      e[c] = __fadd_rn((float)tot, b_in[c]);
    }
    const float dn = fmaxf(__fsqrt_rn(f_sumsq8(e)), 1e-12f);
#pragma unroll
    for (int c = 0; c < 8; ++c) {
      en[c] = __fdiv_rn(e[c], dn);
      enb[c][tl] = en[c];
    }
    seb[tl] = f_sumsq8(en);
  }
  __syncthreads();

  // phase C: quarter qp scans codes [qp*256, +256) (ascending, strict <)
  {
    float en[8];
#pragma unroll
    for (int c = 0; c < 8; ++c) en[c] = enb[c][tl];
    const float se = seb[tl];
    const int j0 = qp * 256;
    float best = INFINITY;
    int bj = j0;
    const float* cbq = cb16 + (size_t)j0 * 16;  // uniform -> s_load
#pragma unroll 4
    for (int jj = 0; jj < 256; ++jj) {
      const float* row = cbq + jj * 16;
      const float4 lo = *(const float4*)(row);
      const float4 hi = *(const float4*)(row + 4);
      const float sc = row[8];
      float d0 = 0.f;
      d0 = fmaf(en[0], lo.x, d0);
      d0 = fmaf(en[1], lo.y, d0);
      d0 = fmaf(en[2], lo.z, d0);
      d0 = fmaf(en[3], lo.w, d0);
      d0 = fmaf(en[4], hi.x, d0);
      d0 = fmaf(en[5], hi.y, d0);
      d0 = fmaf(en[6], hi.z, d0);
      d0 = fmaf(en[7], hi.w, d0);
      const float dist = __fadd_rn(__fsub_rn(se, __fmul_rn(2.0f, d0)), sc);
      if (dist < best) { best = dist; bj = j0 + jj; }
    }
    cdist[qp][tl] = best;
    cidx[qp][tl] = bj;
  }
  __syncthreads();

  // phase D (tid<256): global first-min (quarters ascending, strict <),
  // idx write, loss partial
  if (tid < 256) {
    float bd = cdist[0][tl];
    int bi = cidx[0][tl];
#pragma unroll
    for (int q = 1; q < 4; ++q) {
      const float dd = cdist[q][tl];
      const int jj = cidx[q][tl];
      if (dd < bd) { bd = dd; bi = jj; }
    }
    oidx[(size_t)b * T_ + t] = (float)bi;

    const float* cp = cbraw + (size_t)bi * 8;
    float lsum = 0.f;
#pragma unroll
    for (int c = 0; c < 8; ++c) {
      const float df = __fsub_rn(e[c], cp[c]);
      lsum = fmaf(df, df, lsum);
    }
#pragma unroll
    for (int off = 32; off > 0; off >>= 1)
      lsum += __shfl_down(lsum, off, 64);
    if ((tid & 63) == 0) lred[tid >> 6] = lsum;
  }
  __syncthreads();
  if (tid == 0) {
    float s = 0.f;
#pragma unroll
    for (int w = 0; w < 4; ++w) s += lred[w];
    lossp[blk] = s;
  }
}

// K3: back-projection write-streamer. Block = (b, 32-d slice) covering
// ALL 4096 t -> stores are full contiguous 16-KB rows.
__global__ __launch_bounds__(1024, 4) void vq_out2(
    const float* __restrict__ cbraw, const float* __restrict__ wo16,
    const float* __restrict__ oidx, float* __restrict__ out) {
  const int tid = threadIdx.x;
  const int blk = blockIdx.x;  // b*32 + ds
  const int b = blk >> 5;
  const int ds = blk & 31;
  const int t0 = tid * 4;

  const float4 iv = *(const float4*)(oidx + (size_t)b * T_ + t0);
  const int i0 = (int)iv.x, i1 = (int)iv.y, i2 = (int)iv.z, i3 = (int)iv.w;
  float cq0[8], cq1[8], cq2[8], cq3[8];
  {
    const float* p0 = cbraw + (size_t)i0 * 8;
    const float* p1 = cbraw + (size_t)i1 * 8;
    const float* p2 = cbraw + (size_t)i2 * 8;
    const float* p3 = cbraw + (size_t)i3 * 8;
#pragma unroll
    for (int c = 0; c < 8; ++c) {
      cq0[c] = p0[c]; cq1[c] = p1[c]; cq2[c] = p2[c]; cq3[c] = p3[c];
    }
  }

  const float* woq = wo16 + (size_t)ds * 32 * 16;  // uniform -> s_load
  float* op = out + ((size_t)b * D_ + (size_t)ds * 32) * T_ + t0;
#pragma unroll 4
  for (int d = 0; d < 32; ++d) {
    const float* row = woq + d * 16;
    const float4 lo = *(const float4*)(row);
    const float4 hi = *(const float4*)(row + 4);
    const float bo = row[8];
    float d0 = 0.f, d1 = 0.f, d2 = 0.f, d3 = 0.f;
    d0 = fmaf(cq0[0], lo.x, d0); d1 = fmaf(cq1[0], lo.x, d1);
    d2 = fmaf(cq2[0], lo.x, d2); d3 = fmaf(cq3[0], lo.x, d3);
    d0 = fmaf(cq0[1], lo.y, d0); d1 = fmaf(cq1[1], lo.y, d1);
    d2 = fmaf(cq2[1], lo.y, d2); d3 = fmaf(cq3[1], lo.y, d3);
    d0 = fmaf(cq0[2], lo.z, d0); d1 = fmaf(cq1[2], lo.z, d1);
    d2 = fmaf(cq2[2], lo.z, d2); d3 = fmaf(cq3[2], lo.z, d3);
    d0 = fmaf(cq0[3], lo.w, d0); d1 = fmaf(cq1[3], lo.w, d1);
    d2 = fmaf(cq2[3], lo.w, d2); d3 = fmaf(cq3[3], lo.w, d3);
    d0 = fmaf(cq0[4], hi.x, d0); d1 = fmaf(cq1[4], hi.x, d1);
    d2 = fmaf(cq2[4], hi.x, d2); d3 = fmaf(cq3[4], hi.x, d3);
    d0 = fmaf(cq0[5], hi.y, d0); d1 = fmaf(cq1[5], hi.y, d1);
    d2 = fmaf(cq2[5], hi.y, d2); d3 = fmaf(cq3[5], hi.y, d3);
    d0 = fmaf(cq0[6], hi.z, d0); d1 = fmaf(cq1[6], hi.z, d1);
    d2 = fmaf(cq2[6], hi.z, d2); d3 = fmaf(cq3[6], hi.z, d3);
    d0 = fmaf(cq0[7], hi.w, d0); d1 = fmaf(cq1[7], hi.w, d1);
    d2 = fmaf(cq2[7], hi.w, d2); d3 = fmaf(cq3[7], hi.w, d3);
    float4 ov;
    ov.x = __fadd_rn(d0, bo); ov.y = __fadd_rn(d1, bo);
    ov.z = __fadd_rn(d2, bo); ov.w = __fadd_rn(d3, bo);
    *(float4*)(op + (size_t)d * T_) = ov;
  }
}

// ================= fused fallback (R10, verbatim) =================
__global__ __launch_bounds__(1024, 8) void vq_main(
    const float* __restrict__ z, const float* __restrict__ cbraw,
    const float* __restrict__ b_in, const double* __restrict__ WTd,
    const float* __restrict__ cb16, const float* __restrict__ wo16,
    float* __restrict__ out, float* __restrict__ oidx,
    float* __restrict__ lossp) {
  __shared__ double accb[8704];
  const int tid = threadIdx.x;
  const int q0 = __builtin_amdgcn_readfirstlane(tid >> 6);
  const int tl = tid & 63;
  const int blk = blockIdx.x;
  const int b = blk >> 5;
  const int tile = blk & 31;
  const int t0 = tile * 128 + tl * 2;

  const float2* zp2 =
      (const float2*)(z + ((size_t)b * D_ + (size_t)q0 * 64) * T_ + t0);
  const double* wd = WTd + (size_t)q0 * 512;

  double acc0[8], acc1[8];
#pragma unroll
  for (int c = 0; c < 8; ++c) { acc0[c] = 0.0; acc1[c] = 0.0; }

  float2 zA[8], zB[8];
#pragma unroll
  for (int u = 0; u < 8; ++u) zA[u] = zp2[(size_t)u * (T_ / 2)];

#pragma unroll
  for (int dc = 0; dc < 64; dc += 16) {
#pragma unroll
    for (int u = 0; u < 8; ++u)
      zB[u] = zp2[(size_t)(dc + 8 + u) * (T_ / 2)];
#pragma unroll
    for (int u = 0; u < 8; ++u) {
      const double* w = wd + (size_t)(dc + u) * 8;
      const double zx = (double)zA[u].x, zy = (double)zA[u].y;
#pragma unroll
      for (int c = 0; c < 8; ++c) {
        acc0[c] = fma(zx, w[c], acc0[c]);
        acc1[c] = fma(zy, w[c], acc1[c]);
      }
    }
    if (dc + 16 < 64) {
#pragma unroll
      for (int u = 0; u < 8; ++u)
        zA[u] = zp2[(size_t)(dc + 16 + u) * (T_ / 2)];
    }
#pragma unroll
    for (int u = 0; u < 8; ++u) {
      const double* w = wd + (size_t)(dc + 8 + u) * 8;
      const double zx = (double)zB[u].x, zy = (double)zB[u].y;
#pragma unroll
      for (int c = 0; c < 8; ++c) {
        acc0[c] = fma(zx, w[c], acc0[c]);
        acc1[c] = fma(zy, w[c], acc1[c]);
      }
    }
  }

  double2* accb2 = (double2*)accb;
  double2* totb = accb2 + 4096;
  double tot0[8], tot1[8];
#pragma unroll
  for (int half = 0; half < 2; ++half) {
    const int c0 = half * 4;
#pragma unroll
    for (int c = 0; c < 4; ++c) {
      double2 v; v.x = acc0[c0 + c]; v.y = acc1[c0 + c];
      accb2[c * 1024 + tid] = v;
    }
    __syncthreads();
    if (tid < 64) {
#pragma unroll
      for (int c = 0; c < 4; ++c) {
        const double2* row = accb2 + c * 1024 + tl;
        double2 s = row[0];
#pragma unroll
        for (int qq = 1; qq < 16; ++qq) {
          const double2 v = row[qq * 64];
          s.x = s.x + v.x;
          s.y = s.y + v.y;
        }
        totb[c * 64 + tl] = s;
      }
    }
    __syncthreads();
#pragma unroll
    for (int c = 0; c < 4; ++c) {
      const double2 s = totb[c * 64 + tl];
      tot0[c0 + c] = s.x; tot1[c0 + c] = s.y;
    }
  }

  float e0[8], e1[8], en0[8], en1[8];
#pragma unroll
  for (int c = 0; c < 8; ++c) {
    e0[c] = __fadd_rn((float)tot0[c], b_in[c]);
    e1[c] = __fadd_rn((float)tot1[c], b_in[c]);
  }
  const float n20 = f_sumsq8(e0), n21 = f_sumsq8(e1);
  const float dn0 = fmaxf(__fsqrt_rn(n20), 1e-12f);
  const float dn1 = fmaxf(__fsqrt_rn(n21), 1e-12f);
#pragma unroll
  for (int c = 0; c < 8; ++c) {
    en0[c] = __fdiv_rn(e0[c], dn0);
    en1[c] = __fdiv_rn(e1[c], dn1);
  }
  const float s_enc0 = f_sumsq8(en0), s_enc1 = f_sumsq8(en1);

  const int j0 = q0 * 64;
  float best0 = INFINITY, best1 = INFINITY;
  int bj0 = j0, bj1 = j0;
  {
    const float* cbq = cb16 + (size_t)j0 * 16;
#pragma unroll 4
    for (int jj = 0; jj < 64; ++jj) {
      const float* row = cbq + jj * 16;
      const float4 lo = *(const float4*)(row);
      const float4 hi = *(const float4*)(row + 4);
      const float sc = row[8];
      float d0 = 0.f, d1 = 0.f;
      d0 = fmaf(en0[0], lo.x, d0); d1 = fmaf(en1[0], lo.x, d1);
      d0 = fmaf(en0[1], lo.y, d0); d1 = fmaf(en1[1], lo.y, d1);
      d0 = fmaf(en0[2], lo.z, d0); d1 = fmaf(en1[2], lo.z, d1);
      d0 = fmaf(en0[3], lo.w, d0); d1 = fmaf(en1[3], lo.w, d1);
      d0 = fmaf(en0[4], hi.x, d0); d1 = fmaf(en1[4], hi.x, d1);
      d0 = fmaf(en0[5], hi.y, d0); d1 = fmaf(en1[5], hi.y, d1);
      d0 = fmaf(en0[6], hi.z, d0); d1 = fmaf(en1[6], hi.z, d1);
      d0 = fmaf(en0[7], hi.w, d0); d1 = fmaf(en1[7], hi.w, d1);
      const float dist0 =
          __fadd_rn(__fsub_rn(s_enc0, __fmul_rn(2.0f, d0)), sc);
      const float dist1 =
          __fadd_rn(__fsub_rn(s_enc1, __fmul_rn(2.0f, d1)), sc);
      if (dist0 < best0) { best0 = dist0; bj0 = j0 + jj; }
      if (dist1 < best1) { best1 = dist1; bj1 = j0 + jj; }
    }
  }

  float* distf0 = (float*)accb;
  int* candj0 = (int*)((char*)accb + 4096);
  float* distf1 = (float*)((char*)accb + 8192);
  int* candj1 = (int*)((char*)accb + 12288);
  int* ibuf = (int*)((char*)accb + 16384);
  distf0[tid] = best0; candj0[tid] = bj0;
  distf1[tid] = best1; candj1[tid] = bj1;
  __syncthreads();

  if (tid < 64) {
    float bd0 = distf0[tl], bd1 = distf1[tl];
    int ci0 = candj0[tl], ci1 = candj1[tl];
#pragma unroll
    for (int qq = 1; qq < 16; ++qq) {
      float dd = distf0[qq * 64 + tl];
      int jj = candj0[qq * 64 + tl];
      if (dd < bd0) { bd0 = dd; ci0 = jj; }
      dd = distf1[qq * 64 + tl];
      jj = candj1[qq * 64 + tl];
      if (dd < bd1) { bd1 = dd; ci1 = jj; }
    }
    ibuf[tl] = ci0; ibuf[64 + tl] = ci1;
    float2 iv; iv.x = (float)ci0; iv.y = (float)ci1;
    *(float2*)(oidx + (size_t)b * T_ + t0) = iv;
  }
  __syncthreads();
  const int bi0 = ibuf[tl];
  const int bi1 = ibuf[64 + tl];

  float cq0[8], cq1[8];
  {
    const float* cp0 = cbraw + (size_t)bi0 * 8;
    const float* cp1 = cbraw + (size_t)bi1 * 8;
#pragma unroll
    for (int c = 0; c < 8; ++c) { cq0[c] = cp0[c]; cq1[c] = cp1[c]; }
  }

  if (tid < 64) {
    float lsum = 0.f;
#pragma unroll
    for (int c = 0; c < 8; ++c) {
      const float df0 = __fsub_rn(e0[c], cq0[c]);
      lsum = fmaf(df0, df0, lsum);
    }
#pragma unroll
    for (int c = 0; c < 8; ++c) {
      const float df1 = __fsub_rn(e1[c], cq1[c]);
      lsum = fmaf(df1, df1, lsum);
    }
#pragma unroll
    for (int off = 32; off > 0; off >>= 1)
      lsum += __shfl_down(lsum, off, 64);
    if (tl == 0) lossp[blk] = lsum;
  }

  float2* op2 =
      (float2*)(out + ((size_t)b * D_ + (size_t)q0 * 64) * T_ + t0);
  const float* woq = wo16 + (size_t)q0 * 1024;
#pragma unroll 4
  for (int d = 0; d < 64; ++d) {
    const float* row = woq + d * 16;
    const float4 lo = *(const float4*)(row);
    const float4 hi = *(const float4*)(row + 4);
    const float bo = row[8];
    float d0 = 0.f, d1 = 0.f;
    d0 = fmaf(cq0[0], lo.x, d0); d1 = fmaf(cq1[0], lo.x, d1);
    d0 = fmaf(cq0[1], lo.y, d0); d1 = fmaf(cq1[1], lo.y, d1);
    d0 = fmaf(cq0[2], lo.z, d0); d1 = fmaf(cq1[2], lo.z, d1);
    d0 = fmaf(cq0[3], lo.w, d0); d1 = fmaf(cq1[3], lo.w, d1);
    d0 = fmaf(cq0[4], hi.x, d0); d1 = fmaf(cq1[4], hi.x, d1);
    d0 = fmaf(cq0[5], hi.y, d0); d1 = fmaf(cq1[5], hi.y, d1);
    d0 = fmaf(cq0[6], hi.z, d0); d1 = fmaf(cq1[6], hi.z, d1);
    d0 = fmaf(cq0[7], hi.w, d0); d1 = fmaf(cq1[7], hi.w, d1);
    float2 ov; ov.x = __fadd_rn(d0, bo); ov.y = __fadd_rn(d1, bo);
    op2[(size_t)d * (T_ / 2)] = ov;
  }
}

// ---------- finalize loss (cnt partials per b, ascending) ----------
__global__ __launch_bounds__(64) void vq_fin(const float* __restrict__ lossp,
                                             float* __restrict__ oloss,
                                             int cnt) {
  const int tid = threadIdx.x;
  if (tid < B_) {
    float s = 0.f;
    for (int i = 0; i < cnt; ++i) s += lossp[tid * cnt + i];
    oloss[tid] = s * (1.25f / 32768.0f);
  }
}

extern "C" void kernel_launch(void* const* d_in, const int* in_sizes, int n_in,
                              void* d_out, int out_size, void* d_ws,
                              size_t ws_size, hipStream_t stream) {
  (void)in_sizes; (void)n_in; (void)out_size;
  const float* z = (const float*)d_in[0];
  const float* cb = (const float*)d_in[1];
  const float* g_in = (const float*)d_in[2];
  const float* v_in = (const float*)d_in[3];
  const float* b_in = (const float*)d_in[4];
  const float* g_out = (const float*)d_in[5];
  const float* v_out = (const float*)d_in[6];
  const float* b_out = (const float*)d_in[7];
  float* out = (float*)d_out;

  char* ws = (char*)d_ws;
  double* WTd = (double*)ws;              // 65536 B
  float* cb16 = (float*)(ws + 65536);     // 65536 B
  float* wo16 = (float*)(ws + 131072);    // 65536 B
  float* lossp = (float*)(ws + 196608);   // <= 2048 B
  double* pb = (double*)(ws + 262144);    // 67.1 MB partials

  float* oidx = out + (size_t)B_ * D_ * T_;
  float* oloss = oidx + (size_t)B_ * T_;

  const size_t need = 262144 + (size_t)B_ * 16 * 8 * T_ * 8;  // ~67.4 MB

  vq_setup<<<1, 1024, 0, stream>>>(cb, g_in, v_in, g_out, v_out, b_out, WTd,
                                   cb16, wo16);
  if (ws_size >= need) {
    vq_part<<<512, 1024, 0, stream>>>(z, WTd, pb);
    vq_red<<<256, 1024, 0, stream>>>(pb, cb, b_in, cb16, oidx, lossp);
    vq_out2<<<512, 1024, 0, stream>>>(cb, wo16, oidx, out);
    vq_fin<<<1, 64, 0, stream>>>(lossp, oloss, 16);
  } else {
    vq_main<<<512, 1024, 0, stream>>>(z, cb, b_in, WTd, cb16, wo16, out, oidx,
                                      lossp);
    vq_fin<<<1, 64, 0, stream>>>(lossp, oloss, 32);
  }
}

// Round 16
// 164.839 us; speedup vs baseline: 1.6107x; 1.6107x over previous
//
#include <hip/hip_runtime.h>
#include <math.h>
#include <stdint.h>

#define B_ 16
#define D_ 1024
#define T_ 4096
#define CS_ 1024
#define CD_ 8

// ---------- numpy-mimicking fp32 helpers ----------
__device__ __forceinline__ float f_tree8(const float r[8]) {
  return __fadd_rn(
      __fadd_rn(__fadd_rn(r[0], r[1]), __fadd_rn(r[2], r[3])),
      __fadd_rn(__fadd_rn(r[4], r[5]), __fadd_rn(r[6], r[7])));
}
__device__ __forceinline__ float f_sumsq8(const float x[8]) {
  float s[8];
#pragma unroll
  for (int k = 0; k < 8; ++k) s[k] = __fmul_rn(x[k], x[k]);
  return f_tree8(s);
}

// ---------- setup (unchanged) ----------
__global__ __launch_bounds__(1024) void vq_setup(
    const float* __restrict__ cb, const float* __restrict__ g_in,
    const float* __restrict__ v_in, const float* __restrict__ g_out,
    const float* __restrict__ v_out, const float* __restrict__ b_out,
    double* __restrict__ WTd, float* __restrict__ cb16,
    float* __restrict__ wo16) {
  __shared__ float sv[8 * 1024];
  __shared__ float leafs[64];
  __shared__ float den[8];
  const int tid = threadIdx.x;

  for (int i = tid; i < 8 * 1024; i += 1024) sv[i] = v_in[i];
  __syncthreads();

  if (tid < 64) {
    const int c = tid >> 3, l = tid & 7;
    const float* a = sv + c * 1024 + l * 128;
    float r[8];
#pragma unroll
    for (int k = 0; k < 8; ++k) r[k] = __fmul_rn(a[k], a[k]);
    for (int i = 8; i < 128; i += 8) {
#pragma unroll
      for (int k = 0; k < 8; ++k)
        r[k] = __fadd_rn(r[k], __fmul_rn(a[i + k], a[i + k]));
    }
    leafs[c * 8 + l] = f_tree8(r);
  }
  __syncthreads();
  if (tid < 8) {
    const float* L = leafs + tid * 8;
    float lr[8];
#pragma unroll
    for (int k = 0; k < 8; ++k) lr[k] = L[k];
    const float s = f_tree8(lr);
    den[tid] = fmaxf(__fsqrt_rn(s), 1e-12f);
  }
  __syncthreads();

  if (tid < 1024) {
#pragma unroll
    for (int c = 0; c < 8; ++c) {
      const float w = __fdiv_rn(__fmul_rn(g_in[c], sv[c * 1024 + tid]), den[c]);
      WTd[tid * 8 + c] = (double)w;
    }
    {
      const float* cr = cb + tid * 8;
      float q[8];
#pragma unroll
      for (int c = 0; c < 8; ++c) q[c] = cr[c];
      const float nn = f_sumsq8(q);
      const float dd = fmaxf(__fsqrt_rn(nn), 1e-12f);
      float qn[8];
#pragma unroll
      for (int c = 0; c < 8; ++c) {
        qn[c] = __fdiv_rn(q[c], dd);
        cb16[tid * 16 + c] = qn[c];
      }
      cb16[tid * 16 + 8] = f_sumsq8(qn);
#pragma unroll
      for (int c = 9; c < 16; ++c) cb16[tid * 16 + c] = 0.f;
    }
    {
      const float* vr = v_out + tid * 8;
      float w[8];
#pragma unroll
      for (int c = 0; c < 8; ++c) w[c] = vr[c];
      const float n2 = f_sumsq8(w);
      const float d2 = fmaxf(__fsqrt_rn(n2), 1e-12f);
      const float go = g_out[tid];
#pragma unroll
      for (int c = 0; c < 8; ++c)
        wo16[tid * 16 + c] = __fdiv_rn(__fmul_rn(go, w[c]), d2);
      wo16[tid * 16 + 8] = b_out[tid];
#pragma unroll
      for (int c = 9; c < 16; ++c) wo16[tid * 16 + c] = 0.f;
    }
  }
}

// P1 accumulate macro body (verbatim R10 order): rows ascending, ch inner
#define FMA_ROW(zv, row_d)                                         \
  {                                                                \
    const double* w = wd + (size_t)(row_d) * 8;                    \
    const double zx = (double)(zv).x, zy = (double)(zv).y;         \
    _Pragma("unroll") for (int c = 0; c < 8; ++c) {                \
      acc0[c] = fma(zx, w[c], acc0[c]);                            \
      acc1[c] = fma(zy, w[c], acc1[c]);                            \
    }                                                              \
  }

// P3 single-d store for tile A (cqA in regs)
#define STORE_A(dd)                                                \
  {                                                                \
    const float* row = woq + (dd) * 16;                            \
    const float4 lo = *(const float4*)(row);                       \
    const float4 hi = *(const float4*)(row + 4);                   \
    const float bo = row[8];                                       \
    float o0 = 0.f, o1 = 0.f;                                      \
    o0 = fmaf(cqA0[0], lo.x, o0); o1 = fmaf(cqA1[0], lo.x, o1);    \
    o0 = fmaf(cqA0[1], lo.y, o0); o1 = fmaf(cqA1[1], lo.y, o1);    \
    o0 = fmaf(cqA0[2], lo.z, o0); o1 = fmaf(cqA1[2], lo.z, o1);    \
    o0 = fmaf(cqA0[3], lo.w, o0); o1 = fmaf(cqA1[3], lo.w, o1);    \
    o0 = fmaf(cqA0[4], hi.x, o0); o1 = fmaf(cqA1[4], hi.x, o1);    \
    o0 = fmaf(cqA0[5], hi.y, o0); o1 = fmaf(cqA1[5], hi.y, o1);    \
    o0 = fmaf(cqA0[6], hi.z, o0); o1 = fmaf(cqA1[6], hi.z, o1);    \
    o0 = fmaf(cqA0[7], hi.w, o0); o1 = fmaf(cqA1[7], hi.w, o1);    \
    float2 ov; ov.x = __fadd_rn(o0, bo); ov.y = __fadd_rn(o1, bo); \
    opA[(size_t)(dd) * (T_ / 2)] = ov;                             \
  }

// ---------- main kernel (R16: 2-tile software pipeline) ----------
// Grid: 256 blocks x 1024 threads (16 waves). Block owns 2 adjacent
// 128-t tiles (A,B) of one b; per-tile processing is VERBATIM R10
// (same wave mapping, same f64 order, same strict-< first-min ->
// indices bit-stable). The pipeline folds tile A's P3 stores into
// tile B's P1 load loop (loads issued before stores per chunk, so
// vmcnt FIFO waits for B's loads never require A's stores drained):
// chip-wide, the read stream of tile k+1 overlaps the write stream
// of tile k -- attacking the phase-lockstep that pinned every fused
// variant at ~2.6 TB/s (all co-resident blocks read together, then
// write together; read and write times ADD instead of overlapping).
__global__ __launch_bounds__(1024, 4) void vq_main(
    const float* __restrict__ z, const float* __restrict__ cbraw,
    const float* __restrict__ b_in, const double* __restrict__ WTd,
    const float* __restrict__ cb16, const float* __restrict__ wo16,
    float* __restrict__ out, float* __restrict__ oidx,
    float* __restrict__ lossp) {
  __shared__ double accb[8704];  // 68 KB
  const int tid = threadIdx.x;
  const int q0 = __builtin_amdgcn_readfirstlane(tid >> 6);  // wave 0..15
  const int tl = tid & 63;
  const int blk = blockIdx.x;  // 256 = 16 b * 16 double-tiles
  const int b = blk >> 4;
  const int bt = blk & 15;
  const int t0A = bt * 256 + tl * 2;        // tile A lane t-pair
  const int t0B = bt * 256 + 128 + tl * 2;  // tile B lane t-pair

  const double* wd = WTd + (size_t)q0 * 512;    // uniform -> s_load
  const float* woq = wo16 + (size_t)q0 * 1024;  // uniform -> s_load
  double2* accb2 = (double2*)accb;
  double2* totb = accb2 + 4096;
  float* distf0 = (float*)accb;
  int* candj0 = (int*)((char*)accb + 4096);
  float* distf1 = (float*)((char*)accb + 8192);
  int* candj1 = (int*)((char*)accb + 12288);
  int* ibuf = (int*)((char*)accb + 16384);

  float lossacc = 0.f;

  // ================= TILE A: P1, combine, P2, cand =================
  float eA0[8], eA1[8];
  int biA0, biA1;
  {
    const float2* zp2 =
        (const float2*)(z + ((size_t)b * D_ + (size_t)q0 * 64) * T_ + t0A);
    double acc0[8], acc1[8];
#pragma unroll
    for (int c = 0; c < 8; ++c) { acc0[c] = 0.0; acc1[c] = 0.0; }
    float2 zA[8], zB[8];
#pragma unroll
    for (int u = 0; u < 8; ++u) zA[u] = zp2[(size_t)u * (T_ / 2)];
#pragma unroll
    for (int dc = 0; dc < 64; dc += 16) {
#pragma unroll
      for (int u = 0; u < 8; ++u)
        zB[u] = zp2[(size_t)(dc + 8 + u) * (T_ / 2)];
#pragma unroll
      for (int u = 0; u < 8; ++u) FMA_ROW(zA[u], dc + u)
      if (dc + 16 < 64) {
#pragma unroll
        for (int u = 0; u < 8; ++u)
          zA[u] = zp2[(size_t)(dc + 16 + u) * (T_ / 2)];
      }
#pragma unroll
      for (int u = 0; u < 8; ++u) FMA_ROW(zB[u], dc + 8 + u)
    }

    // combine (wave 0, ascending slices), broadcast
    double tot0[8], tot1[8];
#pragma unroll
    for (int half = 0; half < 2; ++half) {
      const int c0 = half * 4;
#pragma unroll
      for (int c = 0; c < 4; ++c) {
        double2 v; v.x = acc0[c0 + c]; v.y = acc1[c0 + c];
        accb2[c * 1024 + tid] = v;
      }
      __syncthreads();
      if (tid < 64) {
#pragma unroll
        for (int c = 0; c < 4; ++c) {
          const double2* row = accb2 + c * 1024 + tl;
          double2 s = row[0];
#pragma unroll
          for (int qq = 1; qq < 16; ++qq) {
            const double2 v = row[qq * 64];
            s.x = s.x + v.x;
            s.y = s.y + v.y;
          }
          totb[c * 64 + tl] = s;
        }
      }
      __syncthreads();
#pragma unroll
      for (int c = 0; c < 4; ++c) {
        const double2 s = totb[c * 64 + tl];
        tot0[c0 + c] = s.x; tot1[c0 + c] = s.y;
      }
      __syncthreads();
    }

    float en0[8], en1[8];
#pragma unroll
    for (int c = 0; c < 8; ++c) {
      eA0[c] = __fadd_rn((float)tot0[c], b_in[c]);
      eA1[c] = __fadd_rn((float)tot1[c], b_in[c]);
    }
    const float dn0 = fmaxf(__fsqrt_rn(f_sumsq8(eA0)), 1e-12f);
    const float dn1 = fmaxf(__fsqrt_rn(f_sumsq8(eA1)), 1e-12f);
#pragma unroll
    for (int c = 0; c < 8; ++c) {
      en0[c] = __fdiv_rn(eA0[c], dn0);
      en1[c] = __fdiv_rn(eA1[c], dn1);
    }
    const float se0 = f_sumsq8(en0), se1 = f_sumsq8(en1);

    const int j0 = q0 * 64;
    float best0 = INFINITY, best1 = INFINITY;
    int bj0 = j0, bj1 = j0;
    {
      const float* cbq = cb16 + (size_t)j0 * 16;
#pragma unroll 4
      for (int jj = 0; jj < 64; ++jj) {
        const float* row = cbq + jj * 16;
        const float4 lo = *(const float4*)(row);
        const float4 hi = *(const float4*)(row + 4);
        const float sc = row[8];
        float d0 = 0.f, d1 = 0.f;
        d0 = fmaf(en0[0], lo.x, d0); d1 = fmaf(en1[0], lo.x, d1);
        d0 = fmaf(en0[1], lo.y, d0); d1 = fmaf(en1[1], lo.y, d1);
        d0 = fmaf(en0[2], lo.z, d0); d1 = fmaf(en1[2], lo.z, d1);
        d0 = fmaf(en0[3], lo.w, d0); d1 = fmaf(en1[3], lo.w, d1);
        d0 = fmaf(en0[4], hi.x, d0); d1 = fmaf(en1[4], hi.x, d1);
        d0 = fmaf(en0[5], hi.y, d0); d1 = fmaf(en1[5], hi.y, d1);
        d0 = fmaf(en0[6], hi.z, d0); d1 = fmaf(en1[6], hi.z, d1);
        d0 = fmaf(en0[7], hi.w, d0); d1 = fmaf(en1[7], hi.w, d1);
        const float x0 = __fadd_rn(__fsub_rn(se0, __fmul_rn(2.0f, d0)), sc);
        const float x1 = __fadd_rn(__fsub_rn(se1, __fmul_rn(2.0f, d1)), sc);
        if (x0 < best0) { best0 = x0; bj0 = j0 + jj; }
        if (x1 < best1) { best1 = x1; bj1 = j0 + jj; }
      }
    }

    distf0[tid] = best0; candj0[tid] = bj0;
    distf1[tid] = best1; candj1[tid] = bj1;
    __syncthreads();
    if (tid < 64) {
      float bd0 = distf0[tl], bd1 = distf1[tl];
      int ci0 = candj0[tl], ci1 = candj1[tl];
#pragma unroll
      for (int qq = 1; qq < 16; ++qq) {
        float dd = distf0[qq * 64 + tl];
        int jj = candj0[qq * 64 + tl];
        if (dd < bd0) { bd0 = dd; ci0 = jj; }
        dd = distf1[qq * 64 + tl];
        jj = candj1[qq * 64 + tl];
        if (dd < bd1) { bd1 = dd; ci1 = jj; }
      }
      ibuf[tl] = ci0; ibuf[64 + tl] = ci1;
      float2 iv; iv.x = (float)ci0; iv.y = (float)ci1;
      *(float2*)(oidx + (size_t)b * T_ + t0A) = iv;
    }
    __syncthreads();
    biA0 = ibuf[tl];
    biA1 = ibuf[64 + tl];
    __syncthreads();  // all ibuf reads done before tile B reuses accb
  }

  // cqA gather + loss(A)
  float cqA0[8], cqA1[8];
  {
    const float* p0 = cbraw + (size_t)biA0 * 8;
    const float* p1 = cbraw + (size_t)biA1 * 8;
#pragma unroll
    for (int c = 0; c < 8; ++c) { cqA0[c] = p0[c]; cqA1[c] = p1[c]; }
  }
  if (tid < 64) {
    float lsum = 0.f;
#pragma unroll
    for (int c = 0; c < 8; ++c) {
      const float df0 = __fsub_rn(eA0[c], cqA0[c]);
      lsum = fmaf(df0, df0, lsum);
    }
#pragma unroll
    for (int c = 0; c < 8; ++c) {
      const float df1 = __fsub_rn(eA1[c], cqA1[c]);
      lsum = fmaf(df1, df1, lsum);
    }
    lossacc = lsum;
  }

  // ======= TILE B P1 with tile A P3 stores folded in (overlap) =======
  float eB0[8], eB1[8];
  int biB0, biB1;
  {
    float2* opA =
        (float2*)(out + ((size_t)b * D_ + (size_t)q0 * 64) * T_ + t0A);
    const float2* zp2 =
        (const float2*)(z + ((size_t)b * D_ + (size_t)q0 * 64) * T_ + t0B);
    double acc0[8], acc1[8];
#pragma unroll
    for (int c = 0; c < 8; ++c) { acc0[c] = 0.0; acc1[c] = 0.0; }
    float2 zA[8], zB[8];
#pragma unroll
    for (int u = 0; u < 8; ++u) zA[u] = zp2[(size_t)u * (T_ / 2)];
#pragma unroll
    for (int dc = 0; dc < 64; dc += 16) {
      // issue next 8 B-loads, THEN 8 A-stores (stores younger than the
      // loads the next FMA group waits on -> no forced store drain)
#pragma unroll
      for (int u = 0; u < 8; ++u)
        zB[u] = zp2[(size_t)(dc + 8 + u) * (T_ / 2)];
#pragma unroll
      for (int k = 0; k < 8; ++k) STORE_A(dc + k)
#pragma unroll
      for (int u = 0; u < 8; ++u) FMA_ROW(zA[u], dc + u)
      if (dc + 16 < 64) {
#pragma unroll
        for (int u = 0; u < 8; ++u)
          zA[u] = zp2[(size_t)(dc + 16 + u) * (T_ / 2)];
      }
#pragma unroll
      for (int k = 0; k < 8; ++k) STORE_A(dc + 8 + k)
#pragma unroll
      for (int u = 0; u < 8; ++u) FMA_ROW(zB[u], dc + 8 + u)
    }

    // combine (B)
    double tot0[8], tot1[8];
#pragma unroll
    for (int half = 0; half < 2; ++half) {
      const int c0 = half * 4;
#pragma unroll
      for (int c = 0; c < 4; ++c) {
        double2 v; v.x = acc0[c0 + c]; v.y = acc1[c0 + c];
        accb2[c * 1024 + tid] = v;
      }
      __syncthreads();
      if (tid < 64) {
#pragma unroll
        for (int c = 0; c < 4; ++c) {
          const double2* row = accb2 + c * 1024 + tl;
          double2 s = row[0];
#pragma unroll
          for (int qq = 1; qq < 16; ++qq) {
            const double2 v = row[qq * 64];
            s.x = s.x + v.x;
            s.y = s.y + v.y;
          }
          totb[c * 64 + tl] = s;
        }
      }
      __syncthreads();
#pragma unroll
      for (int c = 0; c < 4; ++c) {
        const double2 s = totb[c * 64 + tl];
        tot0[c0 + c] = s.x; tot1[c0 + c] = s.y;
      }
      __syncthreads();
    }

    float en0[8], en1[8];
#pragma unroll
    for (int c = 0; c < 8; ++c) {
      eB0[c] = __fadd_rn((float)tot0[c], b_in[c]);
      eB1[c] = __fadd_rn((float)tot1[c], b_in[c]);
    }
    const float dn0 = fmaxf(__fsqrt_rn(f_sumsq8(eB0)), 1e-12f);
    const float dn1 = fmaxf(__fsqrt_rn(f_sumsq8(eB1)), 1e-12f);
#pragma unroll
    for (int c = 0; c < 8; ++c) {
      en0[c] = __fdiv_rn(eB0[c], dn0);
      en1[c] = __fdiv_rn(eB1[c], dn1);
    }
    const float se0 = f_sumsq8(en0), se1 = f_sumsq8(en1);

    const int j0 = q0 * 64;
    float best0 = INFINITY, best1 = INFINITY;
    int bj0 = j0, bj1 = j0;
    {
      const float* cbq = cb16 + (size_t)j0 * 16;
#pragma unroll 4
      for (int jj = 0; jj < 64; ++jj) {
        const float* row = cbq + jj * 16;
        const float4 lo = *(const float4*)(row);
        const float4 hi = *(const float4*)(row + 4);
        const float sc = row[8];
        float d0 = 0.f, d1 = 0.f;
        d0 = fmaf(en0[0], lo.x, d0); d1 = fmaf(en1[0], lo.x, d1);
        d0 = fmaf(en0[1], lo.y, d0); d1 = fmaf(en1[1], lo.y, d1);
        d0 = fmaf(en0[2], lo.z, d0); d1 = fmaf(en1[2], lo.z, d1);
        d0 = fmaf(en0[3], lo.w, d0); d1 = fmaf(en1[3], lo.w, d1);
        d0 = fmaf(en0[4], hi.x, d0); d1 = fmaf(en1[4], hi.x, d1);
        d0 = fmaf(en0[5], hi.y, d0); d1 = fmaf(en1[5], hi.y, d1);
        d0 = fmaf(en0[6], hi.z, d0); d1 = fmaf(en1[6], hi.z, d1);
        d0 = fmaf(en0[7], hi.w, d0); d1 = fmaf(en1[7], hi.w, d1);
        const float x0 = __fadd_rn(__fsub_rn(se0, __fmul_rn(2.0f, d0)), sc);
        const float x1 = __fadd_rn(__fsub_rn(se1, __fmul_rn(2.0f, d1)), sc);
        if (x0 < best0) { best0 = x0; bj0 = j0 + jj; }
        if (x1 < best1) { best1 = x1; bj1 = j0 + jj; }
      }
    }

    distf0[tid] = best0; candj0[tid] = bj0;
    distf1[tid] = best1; candj1[tid] = bj1;
    __syncthreads();
    if (tid < 64) {
      float bd0 = distf0[tl], bd1 = distf1[tl];
      int ci0 = candj0[tl], ci1 = candj1[tl];
#pragma unroll
      for (int qq = 1; qq < 16; ++qq) {
        float dd = distf0[qq * 64 + tl];
        int jj = candj0[qq * 64 + tl];
        if (dd < bd0) { bd0 = dd; ci0 = jj; }
        dd = distf1[qq * 64 + tl];
        jj = candj1[qq * 64 + tl];
        if (dd < bd1) { bd1 = dd; ci1 = jj; }
      }
      ibuf[tl] = ci0; ibuf[64 + tl] = ci1;
      float2 iv; iv.x = (float)ci0; iv.y = (float)ci1;
      *(float2*)(oidx + (size_t)b * T_ + t0B) = iv;
    }
    __syncthreads();
    biB0 = ibuf[tl];
    biB1 = ibuf[64 + tl];
  }

  // cqB gather + loss(B) + loss write
  float cqB0[8], cqB1[8];
  {
    const float* p0 = cbraw + (size_t)biB0 * 8;
    const float* p1 = cbraw + (size_t)biB1 * 8;
#pragma unroll
    for (int c = 0; c < 8; ++c) { cqB0[c] = p0[c]; cqB1[c] = p1[c]; }
  }
  if (tid < 64) {
    float lsum = lossacc;
#pragma unroll
    for (int c = 0; c < 8; ++c) {
      const float df0 = __fsub_rn(eB0[c], cqB0[c]);
      lsum = fmaf(df0, df0, lsum);
    }
#pragma unroll
    for (int c = 0; c < 8; ++c) {
      const float df1 = __fsub_rn(eB1[c], cqB1[c]);
      lsum = fmaf(df1, df1, lsum);
    }
#pragma unroll
    for (int off = 32; off > 0; off >>= 1)
      lsum += __shfl_down(lsum, off, 64);
    if (tl == 0) lossp[blk] = lsum;
  }

  // P3(B) plain
  {
    float2* opB =
        (float2*)(out + ((size_t)b * D_ + (size_t)q0 * 64) * T_ + t0B);
#pragma unroll 4
    for (int d = 0; d < 64; ++d) {
      const float* row = woq + d * 16;
      const float4 lo = *(const float4*)(row);
      const float4 hi = *(const float4*)(row + 4);
      const float bo = row[8];
      float o0 = 0.f, o1 = 0.f;
      o0 = fmaf(cqB0[0], lo.x, o0); o1 = fmaf(cqB1[0], lo.x, o1);
      o0 = fmaf(cqB0[1], lo.y, o0); o1 = fmaf(cqB1[1], lo.y, o1);
      o0 = fmaf(cqB0[2], lo.z, o0); o1 = fmaf(cqB1[2], lo.z, o1);
      o0 = fmaf(cqB0[3], lo.w, o0); o1 = fmaf(cqB1[3], lo.w, o1);
      o0 = fmaf(cqB0[4], hi.x, o0); o1 = fmaf(cqB1[4], hi.x, o1);
      o0 = fmaf(cqB0[5], hi.y, o0); o1 = fmaf(cqB1[5], hi.y, o1);
      o0 = fmaf(cqB0[6], hi.z, o0); o1 = fmaf(cqB1[6], hi.z, o1);
      o0 = fmaf(cqB0[7], hi.w, o0); o1 = fmaf(cqB1[7], hi.w, o1);
      float2 ov; ov.x = __fadd_rn(o0, bo); ov.y = __fadd_rn(o1, bo);
      opB[(size_t)d * (T_ / 2)] = ov;
    }
  }
}

// ---------- finalize loss (16 double-tile partials per b) ----------
__global__ __launch_bounds__(64) void vq_fin(const float* __restrict__ lossp,
                                             float* __restrict__ oloss) {
  const int tid = threadIdx.x;
  if (tid < B_) {
    float s = 0.f;
    for (int i = 0; i < 16; ++i) s += lossp[tid * 16 + i];
    oloss[tid] = s * (1.25f / 32768.0f);
  }
}

extern "C" void kernel_launch(void* const* d_in, const int* in_sizes, int n_in,
                              void* d_out, int out_size, void* d_ws,
                              size_t ws_size, hipStream_t stream) {
  (void)in_sizes; (void)n_in; (void)out_size; (void)ws_size;
  const float* z = (const float*)d_in[0];
  const float* cb = (const float*)d_in[1];
  const float* g_in = (const float*)d_in[2];
  const float* v_in = (const float*)d_in[3];
  const float* b_in = (const float*)d_in[4];
  const float* g_out = (const float*)d_in[5];
  const float* v_out = (const float*)d_in[6];
  const float* b_out = (const float*)d_in[7];
  float* out = (float*)d_out;

  char* ws = (char*)d_ws;
  double* WTd = (double*)ws;              // 65536 B
  float* cb16 = (float*)(ws + 65536);     // 65536 B
  float* wo16 = (float*)(ws + 131072);    // 65536 B
  float* lossp = (float*)(ws + 196608);   // 1024 B

  float* oidx = out + (size_t)B_ * D_ * T_;
  float* oloss = oidx + (size_t)B_ * T_;

  vq_setup<<<1, 1024, 0, stream>>>(cb, g_in, v_in, g_out, v_out, b_out, WTd,
                                   cb16, wo16);
  vq_main<<<256, 1024, 0, stream>>>(z, cb, b_in, WTd, cb16, wo16, out, oidx,
                                    lossp);
  vq_fin<<<1, 64, 0, stream>>>(lossp, oloss);
}